// Round 6
// baseline (346.496 us; speedup 1.0000x reference)
//
#include <hip/hip_runtime.h>
#include <cstdint>

// Problem dims
#define Bdim 8192   // batch
#define Hdim 1024   // hidden units (per gate)
#define Kdim 2048   // IN + H
// ---- m201-style 8-wave 256-row tile, 4-phase K-step schedule ----
// Block: 256 rows x 64 units x 4 gates (eff-N 256), 512 threads = 8 waves
// as 4M x 2U; wave = 64 rows x 32 units x 4 gates, acc[2][4] floatx16.
// K-step BK=64 = 2 slabs of 32k = 4 kslices of 16; one phase per kslice:
//   READ6 (2A+4B ds_read_b128) ; STAGE group (P1/P2) ; barrier ;
//   lgkmcnt(0) ; setprio(1) ; 8 MFMA ; setprio(0) ; [vmcnt] ; barrier
// Counted vmcnt (T4, never 0 in loop): load groups G(t,S0)/G(t,S1) (4 gload
// each) issued at P1/P2 of step t-1; vmcnt(8) at P2 retires G(t,S1) before
// P3 reads slab1; vmcnt(4) at P4 retires G(t+1,S0) before P1(t+1).
// LDS: 2 bufs x 2 slabs x (256 rows x 32k) x bf16 for A and B = 128 KB,
// 1 block/CU. Slab layout (proven): [row][4 chunks of 8, chunk c at slot
// c^((row>>1)&3)], staged via source-side swizzle + linear gl_lds dest.

#define NSTEP (Kdim / 64)   // 32 K-steps
#define SLAB  (256 * 32)    // elems per slab (A and B identical): 16 KB

#define XELEMS ((size_t)Bdim * Kdim)        // 16,777,216
#define WELEMS ((size_t)4 * Hdim * Kdim)    //  8,388,608
#define WGATE  ((size_t)Hdim * Kdim)        //  2,097,152

typedef __bf16 bf16;
typedef bf16  bf16x8   __attribute__((ext_vector_type(8)));
typedef float floatx16 __attribute__((ext_vector_type(16)));

typedef __attribute__((address_space(1))) uint32_t gu32;
typedef __attribute__((address_space(3))) uint32_t lu32;

__device__ __forceinline__ void gl_lds16(const bf16* g, bf16* l) {
    __builtin_amdgcn_global_load_lds((gu32*)(bf16*)g, (lu32*)l, 16, 0, 0);
}

__device__ __forceinline__ float sigf(float x) {
    return 1.0f / (1.0f + __expf(-x));
}
__device__ __forceinline__ float tanhfast(float x) {
    return 2.0f / (1.0f + __expf(-2.0f * x)) - 1.0f;
}

// ---------------- fp32 -> bf16 conversion pre-pass ----------------
__global__ __launch_bounds__(256) void cvt_kernel(
    const float* __restrict__ inp, const float* __restrict__ hid,
    const float* __restrict__ Wf,  const float* __restrict__ Wi,
    const float* __restrict__ Wo,  const float* __restrict__ Wc,
    bf16* __restrict__ xc, bf16* __restrict__ wc)
{
    const size_t id = (size_t)blockIdx.x * 256 + threadIdx.x;  // 8-elem chunk
    const size_t e  = id * 8;
    const float* src;
    bf16* dst;
    if (e < XELEMS) {
        const size_t b = e >> 11;          // row (K=2048)
        const size_t k = e & (Kdim - 1);
        src = (k < Hdim) ? (hid + b * Hdim + k) : (inp + b * Hdim + (k - Hdim));
        dst = xc + e;
    } else {
        const size_t w = e - XELEMS;
        const size_t g = w >> 21;          // 2^21 == H*K
        const float* Ws = (g == 0) ? Wf : (g == 1) ? Wi : (g == 2) ? Wo : Wc;
        src = Ws + (w & (WGATE - 1));
        dst = wc + w;
    }
    const float4 a  = *reinterpret_cast<const float4*>(src);
    const float4 b4 = *reinterpret_cast<const float4*>(src + 4);
    bf16x8 o;
    o[0] = (bf16)a.x;  o[1] = (bf16)a.y;  o[2] = (bf16)a.z;  o[3] = (bf16)a.w;
    o[4] = (bf16)b4.x; o[5] = (bf16)b4.y; o[6] = (bf16)b4.z; o[7] = (bf16)b4.w;
    *reinterpret_cast<bf16x8*>(dst) = o;
}

// ---------------- fused LSTM GEMM + epilogue ----------------
// 32x32x16 MFMA. A-operand: A[m = lane&31][k = (lane>>5)*8 + j] (B symmetric).
// C/D layout (m74/m101): col = lane&31, row = (reg&3) + 8*(reg>>2) + 4*(lane>>5).
__global__ __launch_bounds__(512, 2) void lstm_fused(
    const bf16* __restrict__ xc,   const bf16* __restrict__ wc,
    const float* __restrict__ cin,
    const float* __restrict__ bfv, const float* __restrict__ biv,
    const float* __restrict__ bov, const float* __restrict__ bcv,
    float* __restrict__ out)
{
    __shared__ __align__(16) bf16 As[4 * SLAB];   // [buf][slab][256r][32k] 64 KB
    __shared__ __align__(16) bf16 Bs[4 * SLAB];   // [buf][slab][4g*64u][32k] 64 KB

    const int tid  = threadIdx.x;
    const int lane = tid & 63;
    const int wv   = tid >> 6;          // 0..7
    const int m31  = lane & 31;
    const int h32  = lane >> 5;

    const int m0 = blockIdx.x * 256;
    const int u0 = blockIdx.y * 64;

    // ---- staging setup (source-side swizzle; LDS dest = base + lane*16) ----
    // per slab: 1024 16B-chunks, 512 threads x 2. li = c*512+tid; row = li>>2.
    const bf16* gA[2];
    bf16* lA[2];
    const bf16* gB[2];
    bf16* lB[2];
    #pragma unroll
    for (int c = 0; c < 2; ++c) {
        const int li   = c * 512 + tid;
        const int row  = li >> 2;           // 0..255
        const int slot = li & 3;
        const int gch  = slot ^ ((row >> 1) & 3);
        gA[c] = xc + (size_t)(m0 + row) * Kdim + gch * 8;
        lA[c] = &As[li * 8];
        const int g  = row >> 6;            // gate
        const int ul = row & 63;            // unit within block
        gB[c] = wc + (size_t)g * WGATE + (size_t)(u0 + ul) * Kdim + gch * 8;
        lB[c] = &Bs[li * 8];
    }

    // ---- fragment read offsets (elements within a slab) ----
    const int rbase = (wv & 3) * 64;    // 4 M-waves
    const int ubase = (wv >> 2) * 32;   // 2 U-waves
    int aoff[2][2];                     // [a: row frag][h: k-half of slab]
    #pragma unroll
    for (int a = 0; a < 2; ++a) {
        const int ra = rbase + a * 32 + m31;
        const int t  = (ra >> 1) & 3;
        #pragma unroll
        for (int h = 0; h < 2; ++h)
            aoff[a][h] = ra * 32 + (((h * 2 + h32) ^ t) * 8);
    }
    int boff[4][2];                     // [g: gate][h]
    #pragma unroll
    for (int g = 0; g < 4; ++g) {
        const int rb = g * 64 + ubase + m31;
        const int t  = (rb >> 1) & 3;
        #pragma unroll
        for (int h = 0; h < 2; ++h)
            boff[g][h] = rb * 32 + (((h * 2 + h32) ^ t) * 8);
    }

    floatx16 acc[2][4] = {};            // [a: row frag][g: gate]

    // stage one 4-load group: slab s of step t into buffer buf
#define STAGE_G(buf, s, t) do {                                     \
        const int kk_  = (t) * 64 + (s) * 32;                       \
        const int off_ = ((buf) * 2 + (s)) * SLAB;                  \
        gl_lds16(gA[0] + kk_, lA[0] + off_);                        \
        gl_lds16(gA[1] + kk_, lA[1] + off_);                        \
        gl_lds16(gB[0] + kk_, lB[0] + off_);                        \
        gl_lds16(gB[1] + kk_, lB[1] + off_);                        \
    } while (0)

    bf16x8 fA[2], fB[4];
#define READ6(buf, s, h) do {                                                 \
        const bf16* Ab_ = As + ((buf) * 2 + (s)) * SLAB;                      \
        const bf16* Bb_ = Bs + ((buf) * 2 + (s)) * SLAB;                      \
        fA[0] = *reinterpret_cast<const bf16x8*>(Ab_ + aoff[0][h]);           \
        fA[1] = *reinterpret_cast<const bf16x8*>(Ab_ + aoff[1][h]);           \
        fB[0] = *reinterpret_cast<const bf16x8*>(Bb_ + boff[0][h]);           \
        fB[1] = *reinterpret_cast<const bf16x8*>(Bb_ + boff[1][h]);           \
        fB[2] = *reinterpret_cast<const bf16x8*>(Bb_ + boff[2][h]);           \
        fB[3] = *reinterpret_cast<const bf16x8*>(Bb_ + boff[3][h]);           \
    } while (0)

#define MFMA8() do {                                                          \
        __builtin_amdgcn_s_setprio(1);                                        \
        _Pragma("unroll")                                                     \
        for (int a_ = 0; a_ < 2; ++a_)                                        \
            _Pragma("unroll")                                                 \
            for (int g_ = 0; g_ < 4; ++g_)                                    \
                acc[a_][g_] = __builtin_amdgcn_mfma_f32_32x32x16_bf16(        \
                    fA[a_], fB[g_], acc[a_][g_], 0, 0, 0);                    \
        __builtin_amdgcn_s_setprio(0);                                        \
    } while (0)

#define BAR() do {                                                            \
        __builtin_amdgcn_s_barrier();                                         \
        asm volatile("" ::: "memory");                                        \
    } while (0)
#define LGKM0() asm volatile("s_waitcnt lgkmcnt(0)" ::: "memory")

    // ---- prologue: step0 both slabs into buf0; S0 landed before P1(0) ----
    STAGE_G(0, 0, 0);
    STAGE_G(0, 1, 0);
    asm volatile("s_waitcnt vmcnt(4)" ::: "memory");   // G(0,S0) landed (own)
    BAR();
    // invariant entering step t: outstanding = {G(t,S1)} = 4

    // one K-step: 4 phases. buf = t&1 (compile-time via x2 unroll).
#define KSTEP(buf, t) do {                                          \
        /* P1: ks0 */                                               \
        READ6(buf, 0, 0);                                           \
        STAGE_G((buf) ^ 1, 0, ((t) + 1) & (NSTEP - 1));             \
        BAR(); LGKM0(); MFMA8();                                    \
        BAR();                                                      \
        /* P2: ks1 */                                               \
        READ6(buf, 0, 1);                                           \
        STAGE_G((buf) ^ 1, 1, ((t) + 1) & (NSTEP - 1));             \
        BAR(); LGKM0(); MFMA8();                                    \
        /* 12 out -> 8: retires G(t,S1) before P3 reads slab1 */    \
        asm volatile("s_waitcnt vmcnt(8)" ::: "memory");            \
        BAR();                                                      \
        /* P3: ks2 */                                               \
        READ6(buf, 1, 0);                                           \
        BAR(); LGKM0(); MFMA8();                                    \
        BAR();                                                      \
        /* P4: ks3 */                                               \
        READ6(buf, 1, 1);                                           \
        BAR(); LGKM0(); MFMA8();                                    \
        /* 8 out -> 4: retires G(t+1,S0) before P1(t+1) */          \
        asm volatile("s_waitcnt vmcnt(4)" ::: "memory");            \
        BAR();                                                      \
    } while (0)

    #pragma unroll 1
    for (int tt = 0; tt < NSTEP; tt += 2) {
        KSTEP(0, tt);
        KSTEP(1, tt + 1);
    }
#undef KSTEP
#undef BAR
#undef LGKM0
#undef MFMA8
#undef READ6
#undef STAGE_G

    // ---- fused LSTM epilogue (one unit per lane) ----
    const int m_base = m0 + rbase + 4 * h32;
    const int unit   = u0 + ubase + m31;
    const float bff = bfv[unit];
    const float bii = biv[unit];
    const float boo = bov[unit];
    const float bcc = bcv[unit];
    #pragma unroll
    for (int a = 0; a < 2; ++a) {
        #pragma unroll
        for (int rg = 0; rg < 16; ++rg) {
            const int row = m_base + a * 32 + (rg & 3) + 8 * (rg >> 2);
            const size_t off = (size_t)row * Hdim + unit;
            const float fg = sigf(acc[a][0][rg] + bff);
            const float ig = sigf(acc[a][1][rg] + bii);
            const float og = sigf(acc[a][2][rg] + boo);
            const float ch = tanhfast(acc[a][3][rg] + bcc);
            const float cn = fg * cin[off] + ig * ch;
            const float hn = og * tanhfast(cn);
            out[off] = hn;                         // h_new
            out[(size_t)Bdim * Hdim + off] = cn;   // c_new
        }
    }
}

extern "C" void kernel_launch(void* const* d_in, const int* in_sizes, int n_in,
                              void* d_out, int out_size, void* d_ws, size_t ws_size,
                              hipStream_t stream) {
    const float* inputs = (const float*)d_in[0];
    const float* hidden = (const float*)d_in[1];
    const float* cprev  = (const float*)d_in[2];
    const float* Wf     = (const float*)d_in[3];
    const float* bfp    = (const float*)d_in[4];
    const float* Wi     = (const float*)d_in[5];
    const float* bip    = (const float*)d_in[6];
    const float* Wo     = (const float*)d_in[7];
    const float* bop    = (const float*)d_in[8];
    const float* Wc     = (const float*)d_in[9];
    const float* bcp    = (const float*)d_in[10];
    float* out = (float*)d_out;

    const size_t need = (XELEMS + WELEMS) * sizeof(bf16);
    if (ws_size < need) return;
    bf16* xc = (bf16*)d_ws;
    bf16* wc = xc + XELEMS;

    const int cvt_blocks = (int)((XELEMS + WELEMS) / 8 / 256);  // 12288
    cvt_kernel<<<dim3(cvt_blocks), dim3(256), 0, stream>>>(
        inputs, hidden, Wf, Wi, Wo, Wc, xc, wc);

    dim3 grid(Bdim / 256, Hdim / 64);   // 32 x 16 = 512 blocks, 1 block/CU
    lstm_fused<<<grid, dim3(512), 0, stream>>>(
        xc, wc, cprev, bfp, bip, bop, bcp, out);
}

// Round 7
// 338.205 us; speedup vs baseline: 1.0245x; 1.0245x over previous
//
#include <hip/hip_runtime.h>
#include <cstdint>

// Problem dims
#define Bdim 8192   // batch
#define Hdim 1024   // hidden units (per gate)
#define Kdim 2048   // IN + H
// ---- m201-style 8-wave 256-row tile, 2-phase (K=32) K-step schedule ----
// Block: 256 rows x 64 units x 4 gates (eff-N 256), 512 threads = 8 waves
// as 4M x 2U; wave = 64 rows x 32 units x 4 gates, acc[2][4] floatx16.
// K-step BK=64 = 2 slabs of 32k; ONE phase per slab (m201 granularity:
// 16 MFMA per phase):
//   STAGE group (4 gload_lds) ; READ12 (4A+8B ds_read_b128) ; barrier ;
//   [compiler counted lgkm] setprio(1) ; 16 MFMA ; setprio(0) ;
//   vmcnt(4) ; barrier
// Counted vmcnt (T4, never 0): invariant entering step t: outstanding =
// {G(t,S1)} = 4. Phase A stages G(t+1,S0) (->8), vmcnt(4) retires G(t,S1)
// for phase B; phase B stages G(t+1,S1) (->8), vmcnt(4) retires G(t+1,S0)
// for next step's phase A. WAR on buffer rewrite separated by >=2 barriers.
// LDS: 2 bufs x 2 slabs x (256 rows x 32k) x bf16 for A and B = 128 KB,
// 1 block/CU. Slab layout (proven): [row][4 chunks of 8, chunk c at slot
// c^((row>>1)&3)], staged via source-side swizzle + linear gl_lds dest.

#define NSTEP (Kdim / 64)   // 32 K-steps
#define SLAB  (256 * 32)    // elems per slab (A and B identical): 16 KB

#define XELEMS ((size_t)Bdim * Kdim)        // 16,777,216
#define WELEMS ((size_t)4 * Hdim * Kdim)    //  8,388,608
#define WGATE  ((size_t)Hdim * Kdim)        //  2,097,152

typedef __bf16 bf16;
typedef bf16  bf16x8   __attribute__((ext_vector_type(8)));
typedef float floatx16 __attribute__((ext_vector_type(16)));

typedef __attribute__((address_space(1))) uint32_t gu32;
typedef __attribute__((address_space(3))) uint32_t lu32;

__device__ __forceinline__ void gl_lds16(const bf16* g, bf16* l) {
    __builtin_amdgcn_global_load_lds((gu32*)(bf16*)g, (lu32*)l, 16, 0, 0);
}

__device__ __forceinline__ float sigf(float x) {
    return 1.0f / (1.0f + __expf(-x));
}
__device__ __forceinline__ float tanhfast(float x) {
    return 2.0f / (1.0f + __expf(-2.0f * x)) - 1.0f;
}

// ---------------- fp32 -> bf16 conversion pre-pass ----------------
__global__ __launch_bounds__(256) void cvt_kernel(
    const float* __restrict__ inp, const float* __restrict__ hid,
    const float* __restrict__ Wf,  const float* __restrict__ Wi,
    const float* __restrict__ Wo,  const float* __restrict__ Wc,
    bf16* __restrict__ xc, bf16* __restrict__ wc)
{
    const size_t id = (size_t)blockIdx.x * 256 + threadIdx.x;  // 8-elem chunk
    const size_t e  = id * 8;
    const float* src;
    bf16* dst;
    if (e < XELEMS) {
        const size_t b = e >> 11;          // row (K=2048)
        const size_t k = e & (Kdim - 1);
        src = (k < Hdim) ? (hid + b * Hdim + k) : (inp + b * Hdim + (k - Hdim));
        dst = xc + e;
    } else {
        const size_t w = e - XELEMS;
        const size_t g = w >> 21;          // 2^21 == H*K
        const float* Ws = (g == 0) ? Wf : (g == 1) ? Wi : (g == 2) ? Wo : Wc;
        src = Ws + (w & (WGATE - 1));
        dst = wc + w;
    }
    const float4 a  = *reinterpret_cast<const float4*>(src);
    const float4 b4 = *reinterpret_cast<const float4*>(src + 4);
    bf16x8 o;
    o[0] = (bf16)a.x;  o[1] = (bf16)a.y;  o[2] = (bf16)a.z;  o[3] = (bf16)a.w;
    o[4] = (bf16)b4.x; o[5] = (bf16)b4.y; o[6] = (bf16)b4.z; o[7] = (bf16)b4.w;
    *reinterpret_cast<bf16x8*>(dst) = o;
}

// ---------------- fused LSTM GEMM + epilogue ----------------
// 32x32x16 MFMA. A-operand: A[m = lane&31][k = (lane>>5)*8 + j] (B symmetric).
// C/D layout (m74/m101): col = lane&31, row = (reg&3) + 8*(reg>>2) + 4*(lane>>5).
__global__ __launch_bounds__(512, 2) void lstm_fused(
    const bf16* __restrict__ xc,   const bf16* __restrict__ wc,
    const float* __restrict__ cin,
    const float* __restrict__ bfv, const float* __restrict__ biv,
    const float* __restrict__ bov, const float* __restrict__ bcv,
    float* __restrict__ out)
{
    __shared__ __align__(16) bf16 As[4 * SLAB];   // [buf][slab][256r][32k] 64 KB
    __shared__ __align__(16) bf16 Bs[4 * SLAB];   // [buf][slab][4g*64u][32k] 64 KB

    const int tid  = threadIdx.x;
    const int lane = tid & 63;
    const int wv   = tid >> 6;          // 0..7
    const int m31  = lane & 31;
    const int h32  = lane >> 5;

    const int m0 = blockIdx.x * 256;
    const int u0 = blockIdx.y * 64;

    // ---- staging setup (source-side swizzle; LDS dest = base + lane*16) ----
    // per slab: 1024 16B-chunks, 512 threads x 2. li = c*512+tid; row = li>>2.
    const bf16* gA[2];
    bf16* lA[2];
    const bf16* gB[2];
    bf16* lB[2];
    #pragma unroll
    for (int c = 0; c < 2; ++c) {
        const int li   = c * 512 + tid;
        const int row  = li >> 2;           // 0..255
        const int slot = li & 3;
        const int gch  = slot ^ ((row >> 1) & 3);
        gA[c] = xc + (size_t)(m0 + row) * Kdim + gch * 8;
        lA[c] = &As[li * 8];
        const int g  = row >> 6;            // gate
        const int ul = row & 63;            // unit within block
        gB[c] = wc + (size_t)g * WGATE + (size_t)(u0 + ul) * Kdim + gch * 8;
        lB[c] = &Bs[li * 8];
    }

    // ---- fragment read offsets (elements within a slab) ----
    const int rbase = (wv & 3) * 64;    // 4 M-waves
    const int ubase = (wv >> 2) * 32;   // 2 U-waves
    int aoff[2][2];                     // [a: row frag][h: k-half of slab]
    #pragma unroll
    for (int a = 0; a < 2; ++a) {
        const int ra = rbase + a * 32 + m31;
        const int t  = (ra >> 1) & 3;
        #pragma unroll
        for (int h = 0; h < 2; ++h)
            aoff[a][h] = ra * 32 + (((h * 2 + h32) ^ t) * 8);
    }
    int boff[4][2];                     // [g: gate][h]
    #pragma unroll
    for (int g = 0; g < 4; ++g) {
        const int rb = g * 64 + ubase + m31;
        const int t  = (rb >> 1) & 3;
        #pragma unroll
        for (int h = 0; h < 2; ++h)
            boff[g][h] = rb * 32 + (((h * 2 + h32) ^ t) * 8);
    }

    floatx16 acc[2][4] = {};            // [a: row frag][g: gate]
    bf16x8 fA[2][2], fB[4][2];          // [.][h] fragments, one K=32 phase

    // stage one 4-load group: slab s of step t into buffer buf
#define STAGE_G(buf, s, t) do {                                     \
        const int kk_  = (t) * 64 + (s) * 32;                       \
        const int off_ = ((buf) * 2 + (s)) * SLAB;                  \
        gl_lds16(gA[0] + kk_, lA[0] + off_);                        \
        gl_lds16(gA[1] + kk_, lA[1] + off_);                        \
        gl_lds16(gB[0] + kk_, lB[0] + off_);                        \
        gl_lds16(gB[1] + kk_, lB[1] + off_);                        \
    } while (0)

    // 12 ds_read_b128: both k-halves of one slab (h0 group first)
#define READ12(buf, s) do {                                                   \
        const bf16* Ab_ = As + ((buf) * 2 + (s)) * SLAB;                      \
        const bf16* Bb_ = Bs + ((buf) * 2 + (s)) * SLAB;                      \
        fA[0][0] = *reinterpret_cast<const bf16x8*>(Ab_ + aoff[0][0]);        \
        fA[1][0] = *reinterpret_cast<const bf16x8*>(Ab_ + aoff[1][0]);        \
        fB[0][0] = *reinterpret_cast<const bf16x8*>(Bb_ + boff[0][0]);        \
        fB[1][0] = *reinterpret_cast<const bf16x8*>(Bb_ + boff[1][0]);        \
        fB[2][0] = *reinterpret_cast<const bf16x8*>(Bb_ + boff[2][0]);        \
        fB[3][0] = *reinterpret_cast<const bf16x8*>(Bb_ + boff[3][0]);        \
        fA[0][1] = *reinterpret_cast<const bf16x8*>(Ab_ + aoff[0][1]);        \
        fA[1][1] = *reinterpret_cast<const bf16x8*>(Ab_ + aoff[1][1]);        \
        fB[0][1] = *reinterpret_cast<const bf16x8*>(Bb_ + boff[0][1]);        \
        fB[1][1] = *reinterpret_cast<const bf16x8*>(Bb_ + boff[1][1]);        \
        fB[2][1] = *reinterpret_cast<const bf16x8*>(Bb_ + boff[2][1]);        \
        fB[3][1] = *reinterpret_cast<const bf16x8*>(Bb_ + boff[3][1]);        \
    } while (0)

#define MFMA16() do {                                                         \
        __builtin_amdgcn_s_setprio(1);                                        \
        _Pragma("unroll")                                                     \
        for (int h_ = 0; h_ < 2; ++h_)                                        \
            _Pragma("unroll")                                                 \
            for (int a_ = 0; a_ < 2; ++a_)                                    \
                _Pragma("unroll")                                             \
                for (int g_ = 0; g_ < 4; ++g_)                                \
                    acc[a_][g_] = __builtin_amdgcn_mfma_f32_32x32x16_bf16(    \
                        fA[a_][h_], fB[g_][h_], acc[a_][g_], 0, 0, 0);        \
        __builtin_amdgcn_s_setprio(0);                                        \
    } while (0)

#define BAR() do {                                                            \
        __builtin_amdgcn_s_barrier();                                         \
        asm volatile("" ::: "memory");                                        \
    } while (0)

    // ---- prologue: step0 both slabs into buf0 ----
    STAGE_G(0, 0, 0);
    STAGE_G(0, 1, 0);
    asm volatile("s_waitcnt vmcnt(4)" ::: "memory");   // G(0,S0) landed (own)
    BAR();
    // invariant entering step t: outstanding = {G(t,S1)} = 4

    // one phase (K=32): stage next step's slab s, read+MFMA this step's slab s.
    // vmcnt(4): 8 outstanding -> retires the oldest 4 (the slab needed next).
#define PHASE(buf, s, tn) do {                                      \
        STAGE_G((buf) ^ 1, s, tn);                                  \
        READ12(buf, s);                                             \
        BAR();                                                      \
        MFMA16();                                                   \
        asm volatile("s_waitcnt vmcnt(4)" ::: "memory");            \
        BAR();                                                      \
    } while (0)

#define KSTEP(buf, t) do {                                          \
        PHASE(buf, 0, ((t) + 1) & (NSTEP - 1));                     \
        PHASE(buf, 1, ((t) + 1) & (NSTEP - 1));                     \
    } while (0)

    #pragma unroll 1
    for (int tt = 0; tt < NSTEP; tt += 2) {
        KSTEP(0, tt);
        KSTEP(1, tt + 1);
    }
#undef KSTEP
#undef PHASE
#undef BAR
#undef MFMA16
#undef READ12
#undef STAGE_G

    // ---- fused LSTM epilogue (one unit per lane) ----
    const int m_base = m0 + rbase + 4 * h32;
    const int unit   = u0 + ubase + m31;
    const float bff = bfv[unit];
    const float bii = biv[unit];
    const float boo = bov[unit];
    const float bcc = bcv[unit];
    #pragma unroll
    for (int a = 0; a < 2; ++a) {
        #pragma unroll
        for (int rg = 0; rg < 16; ++rg) {
            const int row = m_base + a * 32 + (rg & 3) + 8 * (rg >> 2);
            const size_t off = (size_t)row * Hdim + unit;
            const float fg = sigf(acc[a][0][rg] + bff);
            const float ig = sigf(acc[a][1][rg] + bii);
            const float og = sigf(acc[a][2][rg] + boo);
            const float ch = tanhfast(acc[a][3][rg] + bcc);
            const float cn = fg * cin[off] + ig * ch;
            const float hn = og * tanhfast(cn);
            out[off] = hn;                         // h_new
            out[(size_t)Bdim * Hdim + off] = cn;   // c_new
        }
    }
}

extern "C" void kernel_launch(void* const* d_in, const int* in_sizes, int n_in,
                              void* d_out, int out_size, void* d_ws, size_t ws_size,
                              hipStream_t stream) {
    const float* inputs = (const float*)d_in[0];
    const float* hidden = (const float*)d_in[1];
    const float* cprev  = (const float*)d_in[2];
    const float* Wf     = (const float*)d_in[3];
    const float* bfp    = (const float*)d_in[4];
    const float* Wi     = (const float*)d_in[5];
    const float* bip    = (const float*)d_in[6];
    const float* Wo     = (const float*)d_in[7];
    const float* bop    = (const float*)d_in[8];
    const float* Wc     = (const float*)d_in[9];
    const float* bcp    = (const float*)d_in[10];
    float* out = (float*)d_out;

    const size_t need = (XELEMS + WELEMS) * sizeof(bf16);
    if (ws_size < need) return;
    bf16* xc = (bf16*)d_ws;
    bf16* wc = xc + XELEMS;

    const int cvt_blocks = (int)((XELEMS + WELEMS) / 8 / 256);  // 12288
    cvt_kernel<<<dim3(cvt_blocks), dim3(256), 0, stream>>>(
        inputs, hidden, Wf, Wi, Wo, Wc, xc, wc);

    dim3 grid(Bdim / 256, Hdim / 64);   // 32 x 16 = 512 blocks, 1 block/CU
    lstm_fused<<<grid, dim3(512), 0, stream>>>(
        xc, wc, cprev, bfp, bip, bop, bcp, out);
}

// Round 8
// 335.500 us; speedup vs baseline: 1.0328x; 1.0081x over previous
//
#include <hip/hip_runtime.h>
#include <cstdint>

// Problem dims
#define Bdim 8192   // batch
#define Hdim 1024   // hidden units (per gate)
#define Kdim 2048   // IN + H
// ---- 8-wave 256-row tile, per-slab phases, PREFETCH DEPTH 3 (4-slot LDS) ----
// Block: 256 rows x 64 units x 4 gates (eff-N 256), 512 threads = 8 waves
// as 4M x 2U; wave = 64 rows x 32 units x 4 gates, acc[2][4] floatx16.
// 64 phases, one 32-k slab each:
//   STAGE slab p+3 -> slot (p+3)%4 ; READ12 slot p%4 ; barrier ;
//   [compiler counted lgkm] setprio(1) ; 16 MFMA ; setprio(0) ;
//   vmcnt(8) ; barrier
// Ledger (T4, never 0): entering phase p outstanding = {G(p+1),G(p+2)} = 8;
// stage -> 12; vmcnt(8) retires G(p+1) (FIFO). Loads get ~2.5 phases of
// latency cover (the m201 depth-3 discipline). WAR: slot (p+3)%4 = (p-1)%4,
// read at p-1, retired before p-1's closing barrier. Tail stages clamp to
// slab 63 (redundant copies keep the vmcnt count uniform).
// LDS: 4 slab-slots x (256 rows x 32k) x bf16 for A and B = 128 KB, 1 blk/CU.
// Slab layout (proven): [row][4 chunks of 8, chunk c at slot c^((row>>1)&3)],
// staged via source-side swizzle + linear gl_lds dest.

#define NSLAB (Kdim / 32)   // 64 slabs
#define SLAB  (256 * 32)    // elems per slab (A and B identical): 16 KB

#define XELEMS ((size_t)Bdim * Kdim)        // 16,777,216
#define WELEMS ((size_t)4 * Hdim * Kdim)    //  8,388,608
#define WGATE  ((size_t)Hdim * Kdim)        //  2,097,152

typedef __bf16 bf16;
typedef bf16  bf16x8   __attribute__((ext_vector_type(8)));
typedef float floatx16 __attribute__((ext_vector_type(16)));

typedef __attribute__((address_space(1))) uint32_t gu32;
typedef __attribute__((address_space(3))) uint32_t lu32;

__device__ __forceinline__ void gl_lds16(const bf16* g, bf16* l) {
    __builtin_amdgcn_global_load_lds((gu32*)(bf16*)g, (lu32*)l, 16, 0, 0);
}

__device__ __forceinline__ float sigf(float x) {
    return 1.0f / (1.0f + __expf(-x));
}
__device__ __forceinline__ float tanhfast(float x) {
    return 2.0f / (1.0f + __expf(-2.0f * x)) - 1.0f;
}

// ---------------- fp32 -> bf16 conversion pre-pass ----------------
__global__ __launch_bounds__(256) void cvt_kernel(
    const float* __restrict__ inp, const float* __restrict__ hid,
    const float* __restrict__ Wf,  const float* __restrict__ Wi,
    const float* __restrict__ Wo,  const float* __restrict__ Wc,
    bf16* __restrict__ xc, bf16* __restrict__ wc)
{
    const size_t id = (size_t)blockIdx.x * 256 + threadIdx.x;  // 8-elem chunk
    const size_t e  = id * 8;
    const float* src;
    bf16* dst;
    if (e < XELEMS) {
        const size_t b = e >> 11;          // row (K=2048)
        const size_t k = e & (Kdim - 1);
        src = (k < Hdim) ? (hid + b * Hdim + k) : (inp + b * Hdim + (k - Hdim));
        dst = xc + e;
    } else {
        const size_t w = e - XELEMS;
        const size_t g = w >> 21;          // 2^21 == H*K
        const float* Ws = (g == 0) ? Wf : (g == 1) ? Wi : (g == 2) ? Wo : Wc;
        src = Ws + (w & (WGATE - 1));
        dst = wc + w;
    }
    const float4 a  = *reinterpret_cast<const float4*>(src);
    const float4 b4 = *reinterpret_cast<const float4*>(src + 4);
    bf16x8 o;
    o[0] = (bf16)a.x;  o[1] = (bf16)a.y;  o[2] = (bf16)a.z;  o[3] = (bf16)a.w;
    o[4] = (bf16)b4.x; o[5] = (bf16)b4.y; o[6] = (bf16)b4.z; o[7] = (bf16)b4.w;
    *reinterpret_cast<bf16x8*>(dst) = o;
}

// ---------------- fused LSTM GEMM + epilogue ----------------
// 32x32x16 MFMA. A-operand: A[m = lane&31][k = (lane>>5)*8 + j] (B symmetric).
// C/D layout (m74/m101): col = lane&31, row = (reg&3) + 8*(reg>>2) + 4*(lane>>5).
__global__ __launch_bounds__(512, 2) void lstm_fused(
    const bf16* __restrict__ xc,   const bf16* __restrict__ wc,
    const float* __restrict__ cin,
    const float* __restrict__ bfv, const float* __restrict__ biv,
    const float* __restrict__ bov, const float* __restrict__ bcv,
    float* __restrict__ out)
{
    __shared__ __align__(16) bf16 As[4 * SLAB];   // [slot][256r][32k] 64 KB
    __shared__ __align__(16) bf16 Bs[4 * SLAB];   // [slot][4g*64u][32k] 64 KB

    const int tid  = threadIdx.x;
    const int lane = tid & 63;
    const int wv   = tid >> 6;          // 0..7
    const int m31  = lane & 31;
    const int h32  = lane >> 5;

    const int m0 = blockIdx.x * 256;
    const int u0 = blockIdx.y * 64;

    // ---- staging setup (source-side swizzle; LDS dest = base + lane*16) ----
    // per slab: 1024 16B-chunks, 512 threads x 2. li = c*512+tid; row = li>>2.
    const bf16* gA[2];
    bf16* lA[2];
    const bf16* gB[2];
    bf16* lB[2];
    #pragma unroll
    for (int c = 0; c < 2; ++c) {
        const int li   = c * 512 + tid;
        const int row  = li >> 2;           // 0..255
        const int slot = li & 3;
        const int gch  = slot ^ ((row >> 1) & 3);
        gA[c] = xc + (size_t)(m0 + row) * Kdim + gch * 8;
        lA[c] = &As[li * 8];
        const int g  = row >> 6;            // gate
        const int ul = row & 63;            // unit within block
        gB[c] = wc + (size_t)g * WGATE + (size_t)(u0 + ul) * Kdim + gch * 8;
        lB[c] = &Bs[li * 8];
    }

    // ---- fragment read offsets (elements within a slab) ----
    const int rbase = (wv & 3) * 64;    // 4 M-waves
    const int ubase = (wv >> 2) * 32;   // 2 U-waves
    int aoff[2][2];                     // [a: row frag][h: k-half of slab]
    #pragma unroll
    for (int a = 0; a < 2; ++a) {
        const int ra = rbase + a * 32 + m31;
        const int t  = (ra >> 1) & 3;
        #pragma unroll
        for (int h = 0; h < 2; ++h)
            aoff[a][h] = ra * 32 + (((h * 2 + h32) ^ t) * 8);
    }
    int boff[4][2];                     // [g: gate][h]
    #pragma unroll
    for (int g = 0; g < 4; ++g) {
        const int rb = g * 64 + ubase + m31;
        const int t  = (rb >> 1) & 3;
        #pragma unroll
        for (int h = 0; h < 2; ++h)
            boff[g][h] = rb * 32 + (((h * 2 + h32) ^ t) * 8);
    }

    floatx16 acc[2][4] = {};            // [a: row frag][g: gate]
    bf16x8 fA[2][2], fB[4][2];          // [.][h] fragments, one slab

    // stage slab p into LDS slot `slot` (4 gload_lds per thread)
#define STAGE_G(slot, p) do {                                       \
        const int kk_  = (p) * 32;                                  \
        const int off_ = (slot) * SLAB;                             \
        gl_lds16(gA[0] + kk_, lA[0] + off_);                        \
        gl_lds16(gA[1] + kk_, lA[1] + off_);                        \
        gl_lds16(gB[0] + kk_, lB[0] + off_);                        \
        gl_lds16(gB[1] + kk_, lB[1] + off_);                        \
    } while (0)

    // 12 ds_read_b128: both k-halves of one slab (h0 group first)
#define READ12(slot) do {                                                     \
        const bf16* Ab_ = As + (slot) * SLAB;                                 \
        const bf16* Bb_ = Bs + (slot) * SLAB;                                 \
        fA[0][0] = *reinterpret_cast<const bf16x8*>(Ab_ + aoff[0][0]);        \
        fA[1][0] = *reinterpret_cast<const bf16x8*>(Ab_ + aoff[1][0]);        \
        fB[0][0] = *reinterpret_cast<const bf16x8*>(Bb_ + boff[0][0]);        \
        fB[1][0] = *reinterpret_cast<const bf16x8*>(Bb_ + boff[1][0]);        \
        fB[2][0] = *reinterpret_cast<const bf16x8*>(Bb_ + boff[2][0]);        \
        fB[3][0] = *reinterpret_cast<const bf16x8*>(Bb_ + boff[3][0]);        \
        fA[0][1] = *reinterpret_cast<const bf16x8*>(Ab_ + aoff[0][1]);        \
        fA[1][1] = *reinterpret_cast<const bf16x8*>(Ab_ + aoff[1][1]);        \
        fB[0][1] = *reinterpret_cast<const bf16x8*>(Bb_ + boff[0][1]);        \
        fB[1][1] = *reinterpret_cast<const bf16x8*>(Bb_ + boff[1][1]);        \
        fB[2][1] = *reinterpret_cast<const bf16x8*>(Bb_ + boff[2][1]);        \
        fB[3][1] = *reinterpret_cast<const bf16x8*>(Bb_ + boff[3][1]);        \
    } while (0)

#define MFMA16() do {                                                         \
        __builtin_amdgcn_s_setprio(1);                                        \
        _Pragma("unroll")                                                     \
        for (int h_ = 0; h_ < 2; ++h_)                                        \
            _Pragma("unroll")                                                 \
            for (int a_ = 0; a_ < 2; ++a_)                                    \
                _Pragma("unroll")                                             \
                for (int g_ = 0; g_ < 4; ++g_)                                \
                    acc[a_][g_] = __builtin_amdgcn_mfma_f32_32x32x16_bf16(    \
                        fA[a_][h_], fB[g_][h_], acc[a_][g_], 0, 0, 0);        \
        __builtin_amdgcn_s_setprio(0);                                        \
    } while (0)

#define BAR() do {                                                            \
        __builtin_amdgcn_s_barrier();                                         \
        asm volatile("" ::: "memory");                                        \
    } while (0)

    // ---- prologue: slabs 0,1,2 -> slots 0,1,2 ----
    STAGE_G(0, 0);
    STAGE_G(1, 1);
    STAGE_G(2, 2);
    asm volatile("s_waitcnt vmcnt(8)" ::: "memory");   // G(0) landed (own)
    BAR();
    // invariant entering phase p: outstanding = {G(p+1), G(p+2)} = 8

    // one phase: stage slab p+3 (clamped) into slot (p+3)%4, compute slab p.
#define PHASE(slot_c, slot_s, p) do {                               \
        const int pn_ = ((p) + 3 < NSLAB) ? (p) + 3 : NSLAB - 1;    \
        STAGE_G(slot_s, pn_);                                       \
        READ12(slot_c);                                             \
        BAR();                                                      \
        MFMA16();                                                   \
        asm volatile("s_waitcnt vmcnt(8)" ::: "memory");            \
        BAR();                                                      \
    } while (0)

    #pragma unroll 1
    for (int pp = 0; pp < NSLAB; pp += 4) {
        PHASE(0, 3, pp);
        PHASE(1, 0, pp + 1);
        PHASE(2, 1, pp + 2);
        PHASE(3, 2, pp + 3);
    }
#undef PHASE
#undef BAR
#undef MFMA16
#undef READ12
#undef STAGE_G

    // ---- fused LSTM epilogue (one unit per lane) ----
    const int m_base = m0 + rbase + 4 * h32;
    const int unit   = u0 + ubase + m31;
    const float bff = bfv[unit];
    const float bii = biv[unit];
    const float boo = bov[unit];
    const float bcc = bcv[unit];
    #pragma unroll
    for (int a = 0; a < 2; ++a) {
        #pragma unroll
        for (int rg = 0; rg < 16; ++rg) {
            const int row = m_base + a * 32 + (rg & 3) + 8 * (rg >> 2);
            const size_t off = (size_t)row * Hdim + unit;
            const float fg = sigf(acc[a][0][rg] + bff);
            const float ig = sigf(acc[a][1][rg] + bii);
            const float og = sigf(acc[a][2][rg] + boo);
            const float ch = tanhfast(acc[a][3][rg] + bcc);
            const float cn = fg * cin[off] + ig * ch;
            const float hn = og * tanhfast(cn);
            out[off] = hn;                         // h_new
            out[(size_t)Bdim * Hdim + off] = cn;   // c_new
        }
    }
}

extern "C" void kernel_launch(void* const* d_in, const int* in_sizes, int n_in,
                              void* d_out, int out_size, void* d_ws, size_t ws_size,
                              hipStream_t stream) {
    const float* inputs = (const float*)d_in[0];
    const float* hidden = (const float*)d_in[1];
    const float* cprev  = (const float*)d_in[2];
    const float* Wf     = (const float*)d_in[3];
    const float* bfp    = (const float*)d_in[4];
    const float* Wi     = (const float*)d_in[5];
    const float* bip    = (const float*)d_in[6];
    const float* Wo     = (const float*)d_in[7];
    const float* bop    = (const float*)d_in[8];
    const float* Wc     = (const float*)d_in[9];
    const float* bcp    = (const float*)d_in[10];
    float* out = (float*)d_out;

    const size_t need = (XELEMS + WELEMS) * sizeof(bf16);
    if (ws_size < need) return;
    bf16* xc = (bf16*)d_ws;
    bf16* wc = xc + XELEMS;

    const int cvt_blocks = (int)((XELEMS + WELEMS) / 8 / 256);  // 12288
    cvt_kernel<<<dim3(cvt_blocks), dim3(256), 0, stream>>>(
        inputs, hidden, Wf, Wi, Wo, Wc, xc, wc);

    dim3 grid(Bdim / 256, Hdim / 64);   // 32 x 16 = 512 blocks, 1 block/CU
    lstm_fused<<<grid, dim3(512), 0, stream>>>(
        xc, wc, cprev, bfp, bip, bop, bcp, out);
}